// Round 15
// baseline (31.303 us; speedup 1.0000x reference)
//
#include <hip/hip_runtime.h>
#include <hip/hip_bf16.h>

#define B_    32
#define H_IN  80
#define T_IN  1600
#define C1_   32
#define H1_   40
#define T1_   800
#define C2_   32
#define H2_   20
#define T2_   400

// tile geometry: 2 h2 rows x 32 t2 cols per tile; block = 2 consecutive t2-tiles
#define TH2   2
#define TT2   32
#define NH1   5            // 2*TH2+1 conv1 rows
#define NT1   65           // conv1 cols
#define NIDX  33           // ceil(NT1/2)
#define RROWS 11           // raw input rows (4*TH2+3)
#define RCOLSW 66          // raw cols in dwords (132 bf16)
#define RWORDS (RROWS * RCOLSW)   // 726 dwords

#define NPOS   (NH1 * NT1)  // 325 conv1 positions
#define NCHUNK 11           // ceil(325/32)

#define WS_W2FRAGS 1152     // 2 mt * 9 tap * 64 lane (16x16x32 A-frags)
#define WS_W1OFF   1152     // short8 index of W1 A-frags
#define WS_TOTAL   1216
#define OUTN  (B_ * C2_ * H2_ * T2_)

#define OSTR  36            // obuf row stride (floats); 144B keeps quads 16B-aligned

typedef unsigned int uint32;
typedef __attribute__((ext_vector_type(8)))  short short8;
typedef __attribute__((ext_vector_type(4)))  float f32x4;
typedef __attribute__((ext_vector_type(16))) float f32x16;
typedef __attribute__((ext_vector_type(2)))  uint32 u32x2;
typedef __attribute__((ext_vector_type(4)))  uint32 u32x4;

__device__ __forceinline__ unsigned short f2bf(float x) {
    __hip_bfloat16 h = __float2bfloat16(x);
    return __builtin_bit_cast(unsigned short, h);
}

// x1 LDS tile: parity-split on t1r + XOR swizzle of the 16B channel-chunk slot.
__device__ __forceinline__ int x1off(int h1r, int t1r, int g) {
    int idx = t1r >> 1;
    int par = t1r & 1;
    return ((par * (NH1 * NIDX) + h1r * NIDX + idx) << 6) + (((g ^ idx) & 3) << 4);
}

// ---- prep: W2 -> conv2 A-frags (16x16x32), W1+b1 -> conv1 A-frag (32x32x16) ----
__global__ void wprep(const float* __restrict__ W2, const float* __restrict__ W1,
                      const float* __restrict__ b1, unsigned short* __restrict__ ws) {
    int i = blockIdx.x * 256 + threadIdx.x;
    if (i < WS_W2FRAGS) {
        int mt   = i / 576;
        int rem  = i - mt * 576;
        int tap  = rem >> 6;
        int lane = rem & 63;
        int lg   = lane >> 4;
        int l15  = lane & 15;
        int c2   = mt * 16 + l15;
        short8 f;
#pragma unroll
        for (int j = 0; j < 8; ++j)
            f[j] = (short)f2bf(W2[((c2 * C1_) + lg * 8 + j) * 9 + tap]);
        *((short8*)ws + i) = f;
    } else if (i < WS_TOTAL) {
        int lane = i - WS_W1OFF;
        int c1 = lane & 31;
        int kb = (lane >> 5) * 8;
        short8 f;
#pragma unroll
        for (int j = 0; j < 8; ++j) {
            int k = kb + j;
            float v = (k < 9) ? W1[c1 * 9 + k] : (k == 9 ? b1[c1] : 0.0f);
            f[j] = (short)f2bf(v);
        }
        *((short8*)ws + i) = f;
    }
}

// raw-tile load into registers (T14 issue-early half)
__device__ __forceinline__ void stage_load(const float* __restrict__ inb, int tid,
                                           int h2base, int t2base, uint32 rv[3]) {
    const int row0 = 4 * h2base - 3;
    const int t0   = 4 * t2base - 3;
#pragma unroll
    for (int k = 0; k < 3; ++k) {
        int pi = tid + k * 256;
        uint32 v = 0u;
        if (pi < RWORDS) {
            int row = pi / RCOLSW;
            int q   = pi - row * RCOLSW;
            int h = row0 + row;
            int t = t0 + 2 * q;
            bool hok = (h >= 0) & (h < H_IN);
            bool ok0 = hok & (t >= 0) & (t < T_IN);
            bool ok1 = hok & (t + 1 >= 0) & (t + 1 < T_IN);
            float v0 = inb[ok0 ? h * T_IN + t     : 0];
            float v1 = inb[ok1 ? h * T_IN + t + 1 : 0];
            v0 = ok0 ? v0 : 0.0f;
            v1 = ok1 ? v1 : 0.0f;
            v = (uint32)f2bf(v0) | ((uint32)f2bf(v1) << 16);
        }
        rv[k] = v;
    }
}

__global__ __launch_bounds__(256, 6) void fused_conv(
    const float* __restrict__ in, const int* __restrict__ seq,
    const float* __restrict__ b2,
    const unsigned short* __restrict__ ws,
    float* __restrict__ out)
{
    __shared__ __align__(16) char   x1mem[2 * NH1 * NIDX * 64];  // 21120 B (reused as obuf)
    __shared__ __align__(16) uint32 raw32[RWORDS];               // 2904 B

    const int tid  = threadIdx.x;
    const int lane = tid & 63;
    const int wv   = tid >> 6;
    const int l15  = lane & 15;
    const int lg   = lane >> 4;
    const int hi   = lane >> 5;
    const int n32  = lane & 31;
    const int b      = blockIdx.z;
    const int h2base = blockIdx.y * TH2;
    const int t2b0   = blockIdx.x * (2 * TT2);   // first of two t2 tiles

    const int L  = seq[b];
    const int L1 = ((L  - 1) >> 1) + 1;
    const int L2 = ((L1 - 1) >> 1) + 1;

    if (blockIdx.x == 0 && blockIdx.y == 0 && tid == 0)
        out[OUTN + b] = (float)L2;

    const float* inb = in + b * (H_IN * T_IN);
    const bool work0 = (t2b0 < L2);
    const bool work1 = (t2b0 + TT2 < L2);   // tile1 beyond T2 implies beyond L2 too

    // weight fragments: once per block (coalesced ws loads)
    const short8 w1f = *((const short8*)ws + WS_W1OFF + lane);
    const int mt    = wv & 1;
    const int strip = wv >> 1;
    short8 afr[9];
#pragma unroll
    for (int tap = 0; tap < 9; ++tap)
        afr[tap] = *((const short8*)ws + (mt * 9 + tap) * 64 + lane);
    float b2r[4];
#pragma unroll
    for (int j = 0; j < 4; ++j) b2r[j] = b2[mt * 16 + lg * 4 + j];

    // prefetch first working tile's raw data into registers
    uint32 rv[3];
    if (work0)      stage_load(inb, tid, h2base, t2b0, rv);
    else if (work1) stage_load(inb, tid, h2base, t2b0 + TT2, rv);

#pragma unroll
    for (int tt = 0; tt < 2; ++tt) {
        const int t2base = t2b0 + tt * TT2;
        const bool workT = tt == 0 ? work0 : work1;

        if (!workT) {
            // zero tile (or phantom tile beyond T2: guards drop all stores)
            const f32x4 z4 = (f32x4){0.f, 0.f, 0.f, 0.f};
#pragma unroll
            for (int k = 0; k < 2; ++k) {
                int i = tid + k * 256;              // 64 rows (c2,r) x 8 quads
                int row = i >> 3, q = i & 7;
                int c2 = row >> 1, r = row & 1;
                int t2g = t2base + 4 * q;
                if (t2g < T2_)
                    __builtin_nontemporal_store(z4,
                        (f32x4*)(out + ((b * C2_ + c2) * H2_ + h2base + r) * T2_ + t2g));
            }
            continue;
        }

        // ---- phase 0: prefetched regs -> LDS raw ----
#pragma unroll
        for (int k = 0; k < 3; ++k) {
            int pi = tid + k * 256;
            if (pi < RWORDS) raw32[pi] = rv[k];
        }
        __syncthreads();

        // ---- phase 1: conv1 via MFMA 32x32x16; chunk = 32 positions ----
        const int h1base = 2 * h2base - 1;
        const int t1base = 2 * t2base - 1;
        for (int c = wv; c < NCHUNK; c += 4) {
            int p  = c * 32 + n32;
            int pc = p < NPOS ? p : NPOS - 1;
            int h1r = pc / NT1;
            int t1r = pc - h1r * NT1;

            const uint32* rp = raw32 + (2 * h1r) * RCOLSW + t1r;
            uint32 a0 = rp[0],            b0v = rp[1];
            uint32 a1 = rp[RCOLSW],       b1v = rp[RCOLSW + 1];
            uint32 a2 = rp[2 * RCOLSW],   b2v = rp[2 * RCOLSW + 1];

            // lo lanes: k0..7 = taps (0,0),(0,1),(0,2),(1,0),(1,1),(1,2),(2,0),(2,1)
            uint32 w0l = a0;
            uint32 w1l = (b0v & 0xffffu) | (a1 << 16);
            uint32 w2l = (a1 >> 16) | (b1v << 16);
            uint32 w3l = a2;
            // hi lanes: k8 = tap (2,2), k9 = 1.0 (bias), rest 0
            uint32 w0h = (b2v & 0xffffu) | 0x3f800000u;

            uint32 fw0 = hi ? w0h : w0l;
            uint32 fw1 = hi ? 0u  : w1l;
            uint32 fw2 = hi ? 0u  : w2l;
            uint32 fw3 = hi ? 0u  : w3l;
            short8 bfrag = __builtin_bit_cast(short8, (u32x4){fw0, fw1, fw2, fw3});

            f32x16 acc = {};
            acc = __builtin_amdgcn_mfma_f32_32x32x16_bf16(w1f, bfrag, acc, 0, 0, 0);

            // epilogue: relu + mask -> bf16 -> x1 LDS
            int h1 = h1base + h1r;
            int t1 = t1base + t1r;
            bool okp = (h1 >= 0) && (t1 >= 0) && (t1 < L1);
            if (p < NPOS) {
#pragma unroll
                for (int g = 0; g < 4; ++g) {
                    float v0 = okp ? fmaxf(acc[4 * g + 0], 0.0f) : 0.0f;
                    float v1 = okp ? fmaxf(acc[4 * g + 1], 0.0f) : 0.0f;
                    float v2 = okp ? fmaxf(acc[4 * g + 2], 0.0f) : 0.0f;
                    float v3 = okp ? fmaxf(acc[4 * g + 3], 0.0f) : 0.0f;
                    u32x2 dw;
                    dw.x = (uint32)f2bf(v0) | ((uint32)f2bf(v1) << 16);
                    dw.y = (uint32)f2bf(v2) | ((uint32)f2bf(v3) << 16);
                    *(u32x2*)(x1mem + x1off(h1r, t1r, g) + hi * 8) = dw;
                }
            }
        }
        __syncthreads();

        // ---- T14: issue next tile's raw loads; HBM latency hides under conv2 ----
        if (tt == 0 && work1)
            stage_load(inb, tid, h2base, t2b0 + TT2, rv);

        // ---- phase 2: conv2 implicit GEMM (16x16x32). wave = (strip, mt) ----
        f32x4 acc2[TH2];
#pragma unroll
        for (int r = 0; r < TH2; ++r) acc2[r] = (f32x4){0.f, 0.f, 0.f, 0.f};

#pragma unroll
        for (int tap = 0; tap < 9; ++tap) {
            const int kh = tap / 3;
            const int kt = tap % 3;
            const int t1r = 2 * (strip * 16 + l15) + kt;
#pragma unroll
            for (int r = 0; r < TH2; ++r) {
                short8 bx = *(const short8*)(x1mem + x1off(2 * r + kh, t1r, lg));
                acc2[r] = __builtin_amdgcn_mfma_f32_16x16x32_bf16(afr[tap], bx, acc2[r], 0, 0, 0);
            }
        }
        __syncthreads();   // x1 reads done; reuse x1mem as obuf [64 rows][OSTR]

        // D layout: col(l15)=t2 within strip, row=(lg*4+j)=c2 within mtile
        float* obuf = (float*)x1mem;
        {
            const int t2 = t2base + strip * 16 + l15;
            const bool vm = (t2 < L2);
#pragma unroll
            for (int r = 0; r < TH2; ++r) {
#pragma unroll
                for (int j = 0; j < 4; ++j) {
                    int c2 = mt * 16 + lg * 4 + j;
                    float v = acc2[r][j] + b2r[j];
                    v = vm ? fmaxf(v, 0.0f) : 0.0f;
                    obuf[(c2 * TH2 + r) * OSTR + strip * 16 + l15] = v;
                }
            }
        }
        __syncthreads();

        // ---- nt f32x4 stores: 1KB/wave segments, bypass L2 ----
#pragma unroll
        for (int k = 0; k < 2; ++k) {
            int i = tid + k * 256;                  // 64 rows x 8 quads
            int row = i >> 3, q = i & 7;
            int c2 = row >> 1, r = row & 1;
            int t2g = t2base + 4 * q;
            f32x4 v = *(const f32x4*)(obuf + row * OSTR + 4 * q);
            if (t2g < T2_)
                __builtin_nontemporal_store(v,
                    (f32x4*)(out + ((b * C2_ + c2) * H2_ + h2base + r) * T2_ + t2g));
        }
        // next iteration's phase-0 barrier orders obuf reads (complete before the
        // stores issued above) against tile1's conv1 x1 writes.
    }
}

extern "C" void kernel_launch(void* const* d_in, const int* in_sizes, int n_in,
                              void* d_out, int out_size, void* d_ws, size_t ws_size,
                              hipStream_t stream) {
    const float* in  = (const float*)d_in[0];
    const int*   seq = (const int*)d_in[1];
    const float* W1  = (const float*)d_in[2];
    const float* b1  = (const float*)d_in[3];
    const float* W2  = (const float*)d_in[4];
    const float* b2  = (const float*)d_in[5];
    float* out = (float*)d_out;
    unsigned short* ws = (unsigned short*)d_ws;

    wprep<<<dim3((WS_TOTAL + 255) / 256), dim3(256), 0, stream>>>(W2, W1, b1, ws);

    dim3 grid(7, H2_ / TH2, B_);   // t2 tile-pairs (2x32), h2 pairs, batch
    fused_conv<<<grid, dim3(256), 0, stream>>>(in, seq, b2, ws, out);
}

// Round 16
// 23.605 us; speedup vs baseline: 1.3262x; 1.3262x over previous
//
#include <hip/hip_runtime.h>
#include <hip/hip_bf16.h>

#define B_    32
#define H_IN  80
#define T_IN  1600
#define C1_   32
#define H1_   40
#define T1_   800
#define C2_   32
#define H2_   20
#define T2_   400

// tile geometry: 2 h2 rows x 32 t2 cols per block
#define TH2   2
#define TT2   32
#define NH1   5            // 2*TH2+1 conv1 rows
#define NT1   65           // conv1 cols
#define NIDX  33           // ceil(NT1/2)
#define RROWS 11           // raw input rows (4*TH2+3)
#define RCOLSW 66          // raw cols in dwords (132 bf16)
#define RWORDS (RROWS * RCOLSW)   // 726 dwords

#define NPOS   (NH1 * NT1)  // 325 conv1 positions
#define NCHUNK 11           // ceil(325/32)

#define WS_W2FRAGS 1152     // 2 mt * 9 tap * 64 lane (16x16x32 A-frags)
#define WS_W1OFF   1152     // short8 index of W1 A-frags
#define WS_TOTAL   1216
#define OUTN  (B_ * C2_ * H2_ * T2_)

#define OSTR  36            // obuf row stride (floats); 144B keeps quads 16B-aligned

typedef unsigned int uint32;
typedef __attribute__((ext_vector_type(8)))  short short8;
typedef __attribute__((ext_vector_type(4)))  float f32x4;
typedef __attribute__((ext_vector_type(16))) float f32x16;
typedef __attribute__((ext_vector_type(2)))  uint32 u32x2;
typedef __attribute__((ext_vector_type(4)))  uint32 u32x4;

__device__ __forceinline__ unsigned short f2bf(float x) {
    __hip_bfloat16 h = __float2bfloat16(x);
    return __builtin_bit_cast(unsigned short, h);
}

// x1 LDS tile: parity-split on t1r + XOR swizzle of the 16B channel-chunk slot.
__device__ __forceinline__ int x1off(int h1r, int t1r, int g) {
    int idx = t1r >> 1;
    int par = t1r & 1;
    return ((par * (NH1 * NIDX) + h1r * NIDX + idx) << 6) + (((g ^ idx) & 3) << 4);
}

// ---- prep: W2 -> conv2 A-frags (16x16x32), W1+b1 -> conv1 A-frag (32x32x16) ----
__global__ void wprep(const float* __restrict__ W2, const float* __restrict__ W1,
                      const float* __restrict__ b1, unsigned short* __restrict__ ws) {
    int i = blockIdx.x * 256 + threadIdx.x;
    if (i < WS_W2FRAGS) {
        int mt   = i / 576;
        int rem  = i - mt * 576;
        int tap  = rem >> 6;
        int lane = rem & 63;
        int lg   = lane >> 4;
        int l15  = lane & 15;
        int c2   = mt * 16 + l15;
        short8 f;
#pragma unroll
        for (int j = 0; j < 8; ++j)
            f[j] = (short)f2bf(W2[((c2 * C1_) + lg * 8 + j) * 9 + tap]);
        *((short8*)ws + i) = f;
    } else if (i < WS_TOTAL) {
        int lane = i - WS_W1OFF;
        int c1 = lane & 31;
        int kb = (lane >> 5) * 8;
        short8 f;
#pragma unroll
        for (int j = 0; j < 8; ++j) {
            int k = kb + j;
            float v = (k < 9) ? W1[c1 * 9 + k] : (k == 9 ? b1[c1] : 0.0f);
            f[j] = (short)f2bf(v);
        }
        *((short8*)ws + i) = f;
    }
}

__global__ __launch_bounds__(256, 6) void fused_conv(
    const float* __restrict__ in, const int* __restrict__ seq,
    const float* __restrict__ b2,
    const unsigned short* __restrict__ ws,
    float* __restrict__ out)
{
    __shared__ __align__(16) char   x1mem[2 * NH1 * NIDX * 64];  // 21120 B (reused as obuf)
    __shared__ __align__(16) uint32 raw32[RWORDS];               // 2904 B

    const int tid  = threadIdx.x;
    const int lane = tid & 63;
    const int wv   = tid >> 6;
    const int l15  = lane & 15;
    const int lg   = lane >> 4;
    const int hi   = lane >> 5;
    const int n32  = lane & 31;
    const int b      = blockIdx.z;
    const int h2base = blockIdx.y * TH2;
    const int t2base = blockIdx.x * TT2;

    const int L  = seq[b];
    const int L1 = ((L  - 1) >> 1) + 1;
    const int L2 = ((L1 - 1) >> 1) + 1;

    if (blockIdx.x == 0 && blockIdx.y == 0 && tid == 0)
        out[OUTN + b] = (float)L2;

    // ---- early-out: whole t-tile beyond L2 -> zeros (nt f32x4 stores) ----
    if (t2base >= L2) {
        const f32x4 z4 = (f32x4){0.f, 0.f, 0.f, 0.f};
#pragma unroll
        for (int k = 0; k < 2; ++k) {
            int i = tid + k * 256;                  // 64 rows (c2,r) x 8 quads
            int row = i >> 3, q = i & 7;
            int c2 = row >> 1, r = row & 1;
            int t2g = t2base + 4 * q;
            if (t2g < T2_)
                __builtin_nontemporal_store(z4,
                    (f32x4*)(out + ((b * C2_ + c2) * H2_ + h2base + r) * T2_ + t2g));
        }
        return;
    }

    // ---- phase 0: stage raw tile as packed bf16 pairs (branch-free, coalesced) ----
    const int row0 = 4 * h2base - 3;
    const int t0   = 4 * t2base - 3;
    const float* inb = in + b * (H_IN * T_IN);
#pragma unroll
    for (int k = 0; k < 3; ++k) {
        int pi = tid + k * 256;
        if (pi < RWORDS) {
            int row = pi / RCOLSW;
            int q   = pi - row * RCOLSW;
            int h = row0 + row;
            int t = t0 + 2 * q;
            bool hok = (h >= 0) & (h < H_IN);
            bool ok0 = hok & (t >= 0) & (t < T_IN);
            bool ok1 = hok & (t + 1 >= 0) & (t + 1 < T_IN);
            float v0 = inb[ok0 ? h * T_IN + t     : 0];
            float v1 = inb[ok1 ? h * T_IN + t + 1 : 0];
            v0 = ok0 ? v0 : 0.0f;
            v1 = ok1 ? v1 : 0.0f;
            raw32[pi] = (uint32)f2bf(v0) | ((uint32)f2bf(v1) << 16);
        }
    }

    // prefetch all weight fragments (coalesced ws loads; overlap staging latency)
    const short8 w1f = *((const short8*)ws + WS_W1OFF + lane);
    const int mt    = wv & 1;
    const int strip = wv >> 1;
    short8 afr[9];
#pragma unroll
    for (int tap = 0; tap < 9; ++tap)
        afr[tap] = *((const short8*)ws + (mt * 9 + tap) * 64 + lane);
    float b2r[4];
#pragma unroll
    for (int j = 0; j < 4; ++j) b2r[j] = b2[mt * 16 + lg * 4 + j];

    __syncthreads();

    // ---- phase 1: conv1 via MFMA 32x32x16; chunk = 32 positions ----
    const int h1base = 2 * h2base - 1;
    const int t1base = 2 * t2base - 1;
    for (int c = wv; c < NCHUNK; c += 4) {
        int p  = c * 32 + n32;
        int pc = p < NPOS ? p : NPOS - 1;
        int h1r = pc / NT1;
        int t1r = pc - h1r * NT1;

        const uint32* rp = raw32 + (2 * h1r) * RCOLSW + t1r;
        uint32 a0 = rp[0],            b0v = rp[1];
        uint32 a1 = rp[RCOLSW],       b1v = rp[RCOLSW + 1];
        uint32 a2 = rp[2 * RCOLSW],   b2v = rp[2 * RCOLSW + 1];

        // lo lanes: k0..7 = taps (0,0),(0,1),(0,2),(1,0),(1,1),(1,2),(2,0),(2,1)
        uint32 w0l = a0;
        uint32 w1l = (b0v & 0xffffu) | (a1 << 16);
        uint32 w2l = (a1 >> 16) | (b1v << 16);
        uint32 w3l = a2;
        // hi lanes: k8 = tap (2,2), k9 = 1.0 (bias), rest 0
        uint32 w0h = (b2v & 0xffffu) | 0x3f800000u;

        uint32 fw0 = hi ? w0h : w0l;
        uint32 fw1 = hi ? 0u  : w1l;
        uint32 fw2 = hi ? 0u  : w2l;
        uint32 fw3 = hi ? 0u  : w3l;
        short8 bfrag = __builtin_bit_cast(short8, (u32x4){fw0, fw1, fw2, fw3});

        f32x16 acc = {};
        acc = __builtin_amdgcn_mfma_f32_32x32x16_bf16(w1f, bfrag, acc, 0, 0, 0);

        // epilogue: relu + mask -> bf16 -> x1 LDS (lane holds 16 channels of one position)
        int h1 = h1base + h1r;
        int t1 = t1base + t1r;
        bool okp = (h1 >= 0) && (t1 >= 0) && (t1 < L1);
        if (p < NPOS) {
#pragma unroll
            for (int g = 0; g < 4; ++g) {
                float v0 = okp ? fmaxf(acc[4 * g + 0], 0.0f) : 0.0f;
                float v1 = okp ? fmaxf(acc[4 * g + 1], 0.0f) : 0.0f;
                float v2 = okp ? fmaxf(acc[4 * g + 2], 0.0f) : 0.0f;
                float v3 = okp ? fmaxf(acc[4 * g + 3], 0.0f) : 0.0f;
                u32x2 dw;
                dw.x = (uint32)f2bf(v0) | ((uint32)f2bf(v1) << 16);
                dw.y = (uint32)f2bf(v2) | ((uint32)f2bf(v3) << 16);
                *(u32x2*)(x1mem + x1off(h1r, t1r, g) + hi * 8) = dw;
            }
        }
    }

    __syncthreads();

    // ---- phase 2: conv2 implicit GEMM (16x16x32). wave = (strip, mt), rows internal ----
    f32x4 acc2[TH2];
#pragma unroll
    for (int r = 0; r < TH2; ++r) acc2[r] = (f32x4){0.f, 0.f, 0.f, 0.f};

#pragma unroll
    for (int tap = 0; tap < 9; ++tap) {
        const int kh = tap / 3;
        const int kt = tap % 3;
        const int t1r = 2 * (strip * 16 + l15) + kt;
#pragma unroll
        for (int r = 0; r < TH2; ++r) {
            short8 bx = *(const short8*)(x1mem + x1off(2 * r + kh, t1r, lg));
            acc2[r] = __builtin_amdgcn_mfma_f32_16x16x32_bf16(afr[tap], bx, acc2[r], 0, 0, 0);
        }
    }

    __syncthreads();   // x1 reads done; reuse x1mem as obuf [64 rows][OSTR]

    // D layout: col(l15)=t2 within strip, row=(lg*4+j)=c2 within mtile
    float* obuf = (float*)x1mem;
    {
        const int t2 = t2base + strip * 16 + l15;
        const bool vm = (t2 < L2);
#pragma unroll
        for (int r = 0; r < TH2; ++r) {
#pragma unroll
            for (int j = 0; j < 4; ++j) {
                int c2 = mt * 16 + lg * 4 + j;
                float v = acc2[r][j] + b2r[j];
                v = vm ? fmaxf(v, 0.0f) : 0.0f;
                obuf[(c2 * TH2 + r) * OSTR + strip * 16 + l15] = v;
            }
        }
    }
    __syncthreads();

    // ---- nt f32x4 stores: 1KB/wave segments, bypass L2 ----
#pragma unroll
    for (int k = 0; k < 2; ++k) {
        int i = tid + k * 256;                  // 64 rows x 8 quads
        int row = i >> 3, q = i & 7;
        int c2 = row >> 1, r = row & 1;
        int t2g = t2base + 4 * q;
        f32x4 v = *(const f32x4*)(obuf + row * OSTR + 4 * q);
        if (t2g < T2_)
            __builtin_nontemporal_store(v,
                (f32x4*)(out + ((b * C2_ + c2) * H2_ + h2base + r) * T2_ + t2g));
    }
}

extern "C" void kernel_launch(void* const* d_in, const int* in_sizes, int n_in,
                              void* d_out, int out_size, void* d_ws, size_t ws_size,
                              hipStream_t stream) {
    const float* in  = (const float*)d_in[0];
    const int*   seq = (const int*)d_in[1];
    const float* W1  = (const float*)d_in[2];
    const float* b1  = (const float*)d_in[3];
    const float* W2  = (const float*)d_in[4];
    const float* b2  = (const float*)d_in[5];
    float* out = (float*)d_out;
    unsigned short* ws = (unsigned short*)d_ws;

    wprep<<<dim3((WS_TOTAL + 255) / 256), dim3(256), 0, stream>>>(W2, W1, b1, ws);

    dim3 grid((T2_ + TT2 - 1) / TT2, H2_ / TH2, B_);   // 13 x 10 x 32
    fused_conv<<<grid, dim3(256), 0, stream>>>(in, seq, b2, ws, out);
}

// Round 17
// 23.066 us; speedup vs baseline: 1.3571x; 1.0233x over previous
//
#include <hip/hip_runtime.h>
#include <hip/hip_bf16.h>

#define B_    32
#define H_IN  80
#define T_IN  1600
#define C1_   32
#define H1_   40
#define T1_   800
#define C2_   32
#define H2_   20
#define T2_   400

// tile geometry: 2 h2 rows x 32 t2 cols per block
#define TH2   2
#define TT2   32
#define NH1   5            // 2*TH2+1 conv1 rows
#define NT1   65           // conv1 cols
#define NIDX  33           // ceil(NT1/2)
#define RROWS 11           // raw input rows (4*TH2+3)
#define RCW   68           // raw bf16-pair dwords per row (even stride, 272B)
#define NX4   (RROWS * 34) // 374 f32x4 stage items (34 quads/row = 136 fp32 >= 134)

#define NPOS   (NH1 * NT1)  // 325 conv1 positions
#define NCHUNK 11           // ceil(325/32)

#define WS_W2FRAGS 1152     // 2 mt * 9 tap * 64 lane (16x16x32 A-frags)
#define WS_W1OFF   1152     // short8 index of W1 A-frags
#define WS_TOTAL   1216
#define OUTN  (B_ * C2_ * H2_ * T2_)

#define OSTR  36            // obuf row stride (floats); 144B keeps quads 16B-aligned

typedef unsigned int uint32;
typedef __attribute__((ext_vector_type(8)))  short short8;
typedef __attribute__((ext_vector_type(4)))  float f32x4;
typedef __attribute__((ext_vector_type(16))) float f32x16;
typedef __attribute__((ext_vector_type(2)))  uint32 u32x2;
typedef __attribute__((ext_vector_type(4)))  uint32 u32x4;

__device__ __forceinline__ unsigned short f2bf(float x) {
    __hip_bfloat16 h = __float2bfloat16(x);
    return __builtin_bit_cast(unsigned short, h);
}

// x1 LDS tile: parity-split on t1r + XOR swizzle of the 16B channel-chunk slot.
__device__ __forceinline__ int x1off(int h1r, int t1r, int g) {
    int idx = t1r >> 1;
    int par = t1r & 1;
    return ((par * (NH1 * NIDX) + h1r * NIDX + idx) << 6) + (((g ^ idx) & 3) << 4);
}

// ---- prep: W2 -> conv2 A-frags (16x16x32), W1+b1 -> conv1 A-frag (32x32x16) ----
__global__ void wprep(const float* __restrict__ W2, const float* __restrict__ W1,
                      const float* __restrict__ b1, unsigned short* __restrict__ ws) {
    int i = blockIdx.x * 256 + threadIdx.x;
    if (i < WS_W2FRAGS) {
        int mt   = i / 576;
        int rem  = i - mt * 576;
        int tap  = rem >> 6;
        int lane = rem & 63;
        int lg   = lane >> 4;
        int l15  = lane & 15;
        int c2   = mt * 16 + l15;
        short8 f;
#pragma unroll
        for (int j = 0; j < 8; ++j)
            f[j] = (short)f2bf(W2[((c2 * C1_) + lg * 8 + j) * 9 + tap]);
        *((short8*)ws + i) = f;
    } else if (i < WS_TOTAL) {
        int lane = i - WS_W1OFF;
        int c1 = lane & 31;
        int kb = (lane >> 5) * 8;
        short8 f;
#pragma unroll
        for (int j = 0; j < 8; ++j) {
            int k = kb + j;
            float v = (k < 9) ? W1[c1 * 9 + k] : (k == 9 ? b1[c1] : 0.0f);
            f[j] = (short)f2bf(v);
        }
        *((short8*)ws + i) = f;
    }
}

__global__ __launch_bounds__(256, 6) void fused_conv(
    const float* __restrict__ in, const int* __restrict__ seq,
    const float* __restrict__ b2,
    const unsigned short* __restrict__ ws,
    float* __restrict__ out)
{
    __shared__ __align__(16) char   x1mem[2 * NH1 * NIDX * 64];  // 21120 B (reused as obuf)
    __shared__ __align__(16) uint32 raw32[RROWS * RCW];          // 2992 B, bf16-pair packed

    const int tid  = threadIdx.x;
    const int lane = tid & 63;
    const int wv   = tid >> 6;
    const int l15  = lane & 15;
    const int lg   = lane >> 4;
    const int hi   = lane >> 5;
    const int n32  = lane & 31;
    const int b      = blockIdx.z;
    const int h2base = blockIdx.y * TH2;
    const int t2base = blockIdx.x * TT2;

    const int L  = seq[b];
    const int L1 = ((L  - 1) >> 1) + 1;
    const int L2 = ((L1 - 1) >> 1) + 1;

    if (blockIdx.x == 0 && blockIdx.y == 0 && tid == 0)
        out[OUTN + b] = (float)L2;

    // ---- early-out: whole t-tile beyond L2 -> zeros (nt f32x4 stores) ----
    if (t2base >= L2) {
        const f32x4 z4 = (f32x4){0.f, 0.f, 0.f, 0.f};
#pragma unroll
        for (int k = 0; k < 2; ++k) {
            int i = tid + k * 256;                  // 64 rows (c2,r) x 8 quads
            int row = i >> 3, q = i & 7;
            int c2 = row >> 1, r = row & 1;
            int t2g = t2base + 4 * q;
            if (t2g < T2_)
                __builtin_nontemporal_store(z4,
                    (f32x4*)(out + ((b * C2_ + c2) * H2_ + h2base + r) * T2_ + t2g));
        }
        return;
    }

    // ---- phase 0: stage raw tile via aligned f32x4 loads -> packed bf16 pairs ----
    // pair grid base tA = 4*t2base - 4 (even, 16B-aligned in fp32). Since t and
    // T_IN are multiples of 4, quads are never partially out-of-range: one mask.
    const int row0 = 4 * h2base - 3;
    const int tA   = 4 * t2base - 4;
    const float* inb = in + b * (H_IN * T_IN);
#pragma unroll
    for (int k = 0; k < 2; ++k) {
        int it = tid + k * 256;
        if (it < NX4) {
            int row = it / 34;
            int j   = it - row * 34;
            int h = row0 + row;
            int t = tA + 4 * j;
            bool okq = (h >= 0) & (h < H_IN) & (t >= 0) & (t < T_IN);
            int basec = okq ? (h * T_IN + t) : 0;
            f32x4 v = *(const f32x4*)(inb + basec);
            float f0 = okq ? v[0] : 0.0f;
            float f1 = okq ? v[1] : 0.0f;
            float f2 = okq ? v[2] : 0.0f;
            float f3 = okq ? v[3] : 0.0f;
            u32x2 dw;
            dw.x = (uint32)f2bf(f0) | ((uint32)f2bf(f1) << 16);
            dw.y = (uint32)f2bf(f2) | ((uint32)f2bf(f3) << 16);
            *(u32x2*)(raw32 + row * RCW + 2 * j) = dw;
        }
    }

    // prefetch all weight fragments (coalesced ws loads; overlap staging latency)
    const short8 w1f = *((const short8*)ws + WS_W1OFF + lane);
    const int mt    = wv & 1;
    const int strip = wv >> 1;
    short8 afr[9];
#pragma unroll
    for (int tap = 0; tap < 9; ++tap)
        afr[tap] = *((const short8*)ws + (mt * 9 + tap) * 64 + lane);
    float b2r[4];
#pragma unroll
    for (int j = 0; j < 4; ++j) b2r[j] = b2[mt * 16 + lg * 4 + j];

    __syncthreads();

    // ---- phase 1: conv1 via MFMA 32x32x16; chunk = 32 positions ----
    // With even-base pairs: tap(r,0)=hi(a_r), tap(r,1)=lo(b_r), tap(r,2)=hi(b_r)
    // where a_r = rp[t1r], b_r = rp[t1r+1] of raw row r (S = 2*t1r+1 -> mA = t1r).
    const int h1base = 2 * h2base - 1;
    const int t1base = 2 * t2base - 1;
    for (int c = wv; c < NCHUNK; c += 4) {
        int p  = c * 32 + n32;
        int pc = p < NPOS ? p : NPOS - 1;
        int h1r = pc / NT1;
        int t1r = pc - h1r * NT1;

        const uint32* rp = raw32 + (2 * h1r) * RCW + t1r;
        uint32 a0 = rp[0],          b0v = rp[1];
        uint32 a1 = rp[RCW],        b1v = rp[RCW + 1];
        uint32 a2 = rp[2 * RCW],    b2v = rp[2 * RCW + 1];

        // lo lanes: k0..7 = taps (0,0),(0,1),(0,2),(1,0),(1,1),(1,2),(2,0),(2,1)
        uint32 w0l = (a0 >> 16) | (b0v << 16);
        uint32 w1l = (b0v >> 16) | (a1 & 0xffff0000u);
        uint32 w2l = b1v;
        uint32 w3l = (a2 >> 16) | (b2v << 16);
        // hi lanes: k8 = tap (2,2), k9 = 1.0 (bias), rest 0
        uint32 w0h = (b2v >> 16) | 0x3f800000u;

        uint32 fw0 = hi ? w0h : w0l;
        uint32 fw1 = hi ? 0u  : w1l;
        uint32 fw2 = hi ? 0u  : w2l;
        uint32 fw3 = hi ? 0u  : w3l;
        short8 bfrag = __builtin_bit_cast(short8, (u32x4){fw0, fw1, fw2, fw3});

        f32x16 acc = {};
        acc = __builtin_amdgcn_mfma_f32_32x32x16_bf16(w1f, bfrag, acc, 0, 0, 0);

        // epilogue: relu + mask -> bf16 -> x1 LDS (lane holds 16 channels of one position)
        int h1 = h1base + h1r;
        int t1 = t1base + t1r;
        bool okp = (h1 >= 0) && (t1 >= 0) && (t1 < L1);
        if (p < NPOS) {
#pragma unroll
            for (int g = 0; g < 4; ++g) {
                float v0 = okp ? fmaxf(acc[4 * g + 0], 0.0f) : 0.0f;
                float v1 = okp ? fmaxf(acc[4 * g + 1], 0.0f) : 0.0f;
                float v2 = okp ? fmaxf(acc[4 * g + 2], 0.0f) : 0.0f;
                float v3 = okp ? fmaxf(acc[4 * g + 3], 0.0f) : 0.0f;
                u32x2 dw;
                dw.x = (uint32)f2bf(v0) | ((uint32)f2bf(v1) << 16);
                dw.y = (uint32)f2bf(v2) | ((uint32)f2bf(v3) << 16);
                *(u32x2*)(x1mem + x1off(h1r, t1r, g) + hi * 8) = dw;
            }
        }
    }

    __syncthreads();

    // ---- phase 2: conv2 implicit GEMM (16x16x32). wave = (strip, mt), rows internal ----
    f32x4 acc2[TH2];
#pragma unroll
    for (int r = 0; r < TH2; ++r) acc2[r] = (f32x4){0.f, 0.f, 0.f, 0.f};

#pragma unroll
    for (int tap = 0; tap < 9; ++tap) {
        const int kh = tap / 3;
        const int kt = tap % 3;
        const int t1r = 2 * (strip * 16 + l15) + kt;
#pragma unroll
        for (int r = 0; r < TH2; ++r) {
            short8 bx = *(const short8*)(x1mem + x1off(2 * r + kh, t1r, lg));
            acc2[r] = __builtin_amdgcn_mfma_f32_16x16x32_bf16(afr[tap], bx, acc2[r], 0, 0, 0);
        }
    }

    __syncthreads();   // x1 reads done; reuse x1mem as obuf [64 rows][OSTR]

    // D layout: col(l15)=t2 within strip, row=(lg*4+j)=c2 within mtile
    float* obuf = (float*)x1mem;
    {
        const int t2 = t2base + strip * 16 + l15;
        const bool vm = (t2 < L2);
#pragma unroll
        for (int r = 0; r < TH2; ++r) {
#pragma unroll
            for (int j = 0; j < 4; ++j) {
                int c2 = mt * 16 + lg * 4 + j;
                float v = acc2[r][j] + b2r[j];
                v = vm ? fmaxf(v, 0.0f) : 0.0f;
                obuf[(c2 * TH2 + r) * OSTR + strip * 16 + l15] = v;
            }
        }
    }
    __syncthreads();

    // ---- nt f32x4 stores: 1KB/wave segments, bypass L2 ----
#pragma unroll
    for (int k = 0; k < 2; ++k) {
        int i = tid + k * 256;                  // 64 rows x 8 quads
        int row = i >> 3, q = i & 7;
        int c2 = row >> 1, r = row & 1;
        int t2g = t2base + 4 * q;
        f32x4 v = *(const f32x4*)(obuf + row * OSTR + 4 * q);
        if (t2g < T2_)
            __builtin_nontemporal_store(v,
                (f32x4*)(out + ((b * C2_ + c2) * H2_ + h2base + r) * T2_ + t2g));
    }
}

extern "C" void kernel_launch(void* const* d_in, const int* in_sizes, int n_in,
                              void* d_out, int out_size, void* d_ws, size_t ws_size,
                              hipStream_t stream) {
    const float* in  = (const float*)d_in[0];
    const int*   seq = (const int*)d_in[1];
    const float* W1  = (const float*)d_in[2];
    const float* b1  = (const float*)d_in[3];
    const float* W2  = (const float*)d_in[4];
    const float* b2  = (const float*)d_in[5];
    float* out = (float*)d_out;
    unsigned short* ws = (unsigned short*)d_ws;

    wprep<<<dim3((WS_TOTAL + 255) / 256), dim3(256), 0, stream>>>(W2, W1, b1, ws);

    dim3 grid((T2_ + TT2 - 1) / TT2, H2_ / TH2, B_);   // 13 x 10 x 32
    fused_conv<<<grid, dim3(256), 0, stream>>>(in, seq, b2, ws, out);
}

// Round 18
// 22.269 us; speedup vs baseline: 1.4057x; 1.0358x over previous
//
#include <hip/hip_runtime.h>
#include <hip/hip_bf16.h>

#define B_    32
#define H_IN  80
#define T_IN  1600
#define C1_   32
#define H1_   40
#define T1_   800
#define C2_   32
#define H2_   20
#define T2_   400

// tile geometry: 2 h2 rows x 32 t2 cols per block
#define TH2   2
#define TT2   32
#define NH1   5            // 2*TH2+1 conv1 rows
#define NT1   65           // conv1 cols
#define NIDX  33           // ceil(NT1/2)
#define RROWS 11           // raw input rows (4*TH2+3)
#define RCW   68           // raw bf16-pair dwords per row (even stride, 272B)
#define NX4   (RROWS * 34) // 374 f32x4 stage items

#define NPOS   (NH1 * NT1)  // 325 conv1 positions
#define NCHUNK 11           // ceil(325/32)

#define WS_W2FRAGS 1152     // 2 mt * 9 tap * 64 lane (16x16x32 A-frags)
#define WS_W1OFF   1152     // short8 index of W1 A-frags
#define WS_TOTAL   1216
#define OUTN  (B_ * C2_ * H2_ * T2_)

typedef unsigned int uint32;
typedef __attribute__((ext_vector_type(8)))  short short8;
typedef __attribute__((ext_vector_type(4)))  float f32x4;
typedef __attribute__((ext_vector_type(16))) float f32x16;
typedef __attribute__((ext_vector_type(2)))  uint32 u32x2;
typedef __attribute__((ext_vector_type(4)))  uint32 u32x4;

__device__ __forceinline__ unsigned short f2bf(float x) {
    __hip_bfloat16 h = __float2bfloat16(x);
    return __builtin_bit_cast(unsigned short, h);
}

// x1 LDS tile: parity-split on t1r + XOR swizzle of the 16B channel-chunk slot.
__device__ __forceinline__ int x1off(int h1r, int t1r, int g) {
    int idx = t1r >> 1;
    int par = t1r & 1;
    return ((par * (NH1 * NIDX) + h1r * NIDX + idx) << 6) + (((g ^ idx) & 3) << 4);
}

// ---- prep: W2 -> conv2 A-frags (16x16x32), W1+b1 -> conv1 A-frag (32x32x16) ----
__global__ void wprep(const float* __restrict__ W2, const float* __restrict__ W1,
                      const float* __restrict__ b1, unsigned short* __restrict__ ws) {
    int i = blockIdx.x * 256 + threadIdx.x;
    if (i < WS_W2FRAGS) {
        int mt   = i / 576;
        int rem  = i - mt * 576;
        int tap  = rem >> 6;
        int lane = rem & 63;
        int lg   = lane >> 4;
        int l15  = lane & 15;
        int c2   = mt * 16 + l15;
        short8 f;
#pragma unroll
        for (int j = 0; j < 8; ++j)
            f[j] = (short)f2bf(W2[((c2 * C1_) + lg * 8 + j) * 9 + tap]);
        *((short8*)ws + i) = f;
    } else if (i < WS_TOTAL) {
        int lane = i - WS_W1OFF;
        int c1 = lane & 31;
        int kb = (lane >> 5) * 8;
        short8 f;
#pragma unroll
        for (int j = 0; j < 8; ++j) {
            int k = kb + j;
            float v = (k < 9) ? W1[c1 * 9 + k] : (k == 9 ? b1[c1] : 0.0f);
            f[j] = (short)f2bf(v);
        }
        *((short8*)ws + i) = f;
    }
}

__global__ __launch_bounds__(256, 6) void fused_conv(
    const float* __restrict__ in, const int* __restrict__ seq,
    const float* __restrict__ b2,
    const unsigned short* __restrict__ ws,
    float* __restrict__ out)
{
    __shared__ __align__(16) char   x1mem[2 * NH1 * NIDX * 64];  // 21120 B
    __shared__ __align__(16) uint32 raw32[RROWS * RCW];          // 2992 B, bf16-pair packed

    const int tid  = threadIdx.x;
    const int lane = tid & 63;
    const int wv   = tid >> 6;
    const int l15  = lane & 15;
    const int lg   = lane >> 4;
    const int hi   = lane >> 5;
    const int n32  = lane & 31;
    const int b      = blockIdx.z;
    const int h2base = blockIdx.y * TH2;
    const int t2base = blockIdx.x * TT2;

    const int L  = seq[b];
    const int L1 = ((L  - 1) >> 1) + 1;
    const int L2 = ((L1 - 1) >> 1) + 1;

    if (blockIdx.x == 0 && blockIdx.y == 0 && tid == 0)
        out[OUTN + b] = (float)L2;

    // ---- early-out: whole t-tile beyond L2 -> zeros (nt f32x4 stores) ----
    if (t2base >= L2) {
        const f32x4 z4 = (f32x4){0.f, 0.f, 0.f, 0.f};
#pragma unroll
        for (int k = 0; k < 2; ++k) {
            int i = tid + k * 256;                  // 64 rows (c2,r) x 8 quads
            int row = i >> 3, q = i & 7;
            int c2 = row >> 1, r = row & 1;
            int t2g = t2base + 4 * q;
            if (t2g < T2_)
                __builtin_nontemporal_store(z4,
                    (f32x4*)(out + ((b * C2_ + c2) * H2_ + h2base + r) * T2_ + t2g));
        }
        return;
    }

    // ---- phase 0: stage raw tile via aligned f32x4 loads -> packed bf16 pairs ----
    const int row0 = 4 * h2base - 3;
    const int tA   = 4 * t2base - 4;
    const float* inb = in + b * (H_IN * T_IN);
#pragma unroll
    for (int k = 0; k < 2; ++k) {
        int it = tid + k * 256;
        if (it < NX4) {
            int row = it / 34;
            int j   = it - row * 34;
            int h = row0 + row;
            int t = tA + 4 * j;
            bool okq = (h >= 0) & (h < H_IN) & (t >= 0) & (t < T_IN);
            int basec = okq ? (h * T_IN + t) : 0;
            f32x4 v = *(const f32x4*)(inb + basec);
            float f0 = okq ? v[0] : 0.0f;
            float f1 = okq ? v[1] : 0.0f;
            float f2 = okq ? v[2] : 0.0f;
            float f3 = okq ? v[3] : 0.0f;
            u32x2 dw;
            dw.x = (uint32)f2bf(f0) | ((uint32)f2bf(f1) << 16);
            dw.y = (uint32)f2bf(f2) | ((uint32)f2bf(f3) << 16);
            *(u32x2*)(raw32 + row * RCW + 2 * j) = dw;
        }
    }

    // prefetch all weight fragments (coalesced ws loads; overlap staging latency)
    const short8 w1f = *((const short8*)ws + WS_W1OFF + lane);
    const int mt    = wv & 1;
    const int strip = wv >> 1;
    short8 afr[9];
#pragma unroll
    for (int tap = 0; tap < 9; ++tap)
        afr[tap] = *((const short8*)ws + (mt * 9 + tap) * 64 + lane);
    float b2r[4];
#pragma unroll
    for (int j = 0; j < 4; ++j) b2r[j] = b2[mt * 16 + lg * 4 + j];

    __syncthreads();

    // ---- phase 1: conv1 via MFMA 32x32x16; chunk = 32 positions ----
    // Even-base pairs: tap(r,0)=hi(a_r), tap(r,1)=lo(b_r), tap(r,2)=hi(b_r),
    // a_r = rp[t1r], b_r = rp[t1r+1].
    const int h1base = 2 * h2base - 1;
    const int t1base = 2 * t2base - 1;
    for (int c = wv; c < NCHUNK; c += 4) {
        int p  = c * 32 + n32;
        int pc = p < NPOS ? p : NPOS - 1;
        int h1r = pc / NT1;
        int t1r = pc - h1r * NT1;

        const uint32* rp = raw32 + (2 * h1r) * RCW + t1r;
        uint32 a0 = rp[0],          b0v = rp[1];
        uint32 a1 = rp[RCW],        b1v = rp[RCW + 1];
        uint32 a2 = rp[2 * RCW],    b2v = rp[2 * RCW + 1];

        // lo lanes: k0..7 = taps (0,0),(0,1),(0,2),(1,0),(1,1),(1,2),(2,0),(2,1)
        uint32 w0l = (a0 >> 16) | (b0v << 16);
        uint32 w1l = (b0v >> 16) | (a1 & 0xffff0000u);
        uint32 w2l = b1v;
        uint32 w3l = (a2 >> 16) | (b2v << 16);
        // hi lanes: k8 = tap (2,2), k9 = 1.0 (bias), rest 0
        uint32 w0h = (b2v >> 16) | 0x3f800000u;

        uint32 fw0 = hi ? w0h : w0l;
        uint32 fw1 = hi ? 0u  : w1l;
        uint32 fw2 = hi ? 0u  : w2l;
        uint32 fw3 = hi ? 0u  : w3l;
        short8 bfrag = __builtin_bit_cast(short8, (u32x4){fw0, fw1, fw2, fw3});

        f32x16 acc = {};
        acc = __builtin_amdgcn_mfma_f32_32x32x16_bf16(w1f, bfrag, acc, 0, 0, 0);

        // epilogue: relu + mask -> bf16 -> x1 LDS (lane holds 16 channels of one position)
        int h1 = h1base + h1r;
        int t1 = t1base + t1r;
        bool okp = (h1 >= 0) && (t1 >= 0) && (t1 < L1);
        if (p < NPOS) {
#pragma unroll
            for (int g = 0; g < 4; ++g) {
                float v0 = okp ? fmaxf(acc[4 * g + 0], 0.0f) : 0.0f;
                float v1 = okp ? fmaxf(acc[4 * g + 1], 0.0f) : 0.0f;
                float v2 = okp ? fmaxf(acc[4 * g + 2], 0.0f) : 0.0f;
                float v3 = okp ? fmaxf(acc[4 * g + 3], 0.0f) : 0.0f;
                u32x2 dw;
                dw.x = (uint32)f2bf(v0) | ((uint32)f2bf(v1) << 16);
                dw.y = (uint32)f2bf(v2) | ((uint32)f2bf(v3) << 16);
                *(u32x2*)(x1mem + x1off(h1r, t1r, g) + hi * 8) = dw;
            }
        }
    }

    __syncthreads();

    // ---- phase 2: conv2 implicit GEMM (16x16x32) + DIRECT nt stores ----
    f32x4 acc2[TH2];
#pragma unroll
    for (int r = 0; r < TH2; ++r) acc2[r] = (f32x4){0.f, 0.f, 0.f, 0.f};

#pragma unroll
    for (int tap = 0; tap < 9; ++tap) {
        const int kh = tap / 3;
        const int kt = tap % 3;
        const int t1r = 2 * (strip * 16 + l15) + kt;
#pragma unroll
        for (int r = 0; r < TH2; ++r) {
            short8 bx = *(const short8*)(x1mem + x1off(2 * r + kh, t1r, lg));
            acc2[r] = __builtin_amdgcn_mfma_f32_16x16x32_bf16(afr[tap], bx, acc2[r], 0, 0, 0);
        }
    }

    // D layout: col = l15 = t2 within strip, row = lg*4+j = c2 within mtile.
    // Store straight from registers: 16-lane groups give 64B contiguous runs;
    // NT bypasses L2 so segment size is less critical than write-allocate path.
    {
        const int t2 = t2base + strip * 16 + l15;
        const bool vm = (t2 < L2);   // t2 < T2_ always (t2base+31 <= 415 < 416 guard below)
        if (t2 < T2_) {
            float* outb = out + ((b * C2_) * H2_ + h2base) * T2_ + t2;
#pragma unroll
            for (int r = 0; r < TH2; ++r) {
#pragma unroll
                for (int j = 0; j < 4; ++j) {
                    int c2 = mt * 16 + lg * 4 + j;
                    float v = acc2[r][j] + b2r[j];
                    v = vm ? fmaxf(v, 0.0f) : 0.0f;
                    __builtin_nontemporal_store(v, outb + (c2 * H2_ + r) * T2_);
                }
            }
        }
    }
}

extern "C" void kernel_launch(void* const* d_in, const int* in_sizes, int n_in,
                              void* d_out, int out_size, void* d_ws, size_t ws_size,
                              hipStream_t stream) {
    const float* in  = (const float*)d_in[0];
    const int*   seq = (const int*)d_in[1];
    const float* W1  = (const float*)d_in[2];
    const float* b1  = (const float*)d_in[3];
    const float* W2  = (const float*)d_in[4];
    const float* b2  = (const float*)d_in[5];
    float* out = (float*)d_out;
    unsigned short* ws = (unsigned short*)d_ws;

    wprep<<<dim3((WS_TOTAL + 255) / 256), dim3(256), 0, stream>>>(W2, W1, b1, ws);

    dim3 grid((T2_ + TT2 - 1) / TT2, H2_ / TH2, B_);   // 13 x 10 x 32
    fused_conv<<<grid, dim3(256), 0, stream>>>(in, seq, b2, ws, out);
}